// Round 1
// baseline (1259.959 us; speedup 1.0000x reference)
//
#include <hip/hip_runtime.h>

#define FLATD 10816
#define KS 32
#define KCH 338   // 10816 / 32

// ---------------- conv1: memory (B,256,16,16) -> h1 (B,32,16,16), SAME ----
__global__ __launch_bounds__(256) void conv1_kernel(
    const float* __restrict__ mem, const float* __restrict__ k1,
    float* __restrict__ h1) {
  const int b = blockIdx.x;
  const int t = threadIdx.x;          // pixel 0..255
  const int y = t >> 4, x = t & 15;
  __shared__ float lm[32 * 256];      // 32 channels x 256 pixels

  float msk[9]; int nid[9];
#pragma unroll
  for (int dy = 0; dy < 3; ++dy)
#pragma unroll
    for (int dx = 0; dx < 3; ++dx) {
      int yy = y + dy - 1, xx = x + dx - 1;
      bool v = ((unsigned)yy < 16u) && ((unsigned)xx < 16u);
      msk[dy * 3 + dx] = v ? 1.f : 0.f;
      nid[dy * 3 + dx] = v ? (yy * 16 + xx) : 0;
    }

  float acc[32];
#pragma unroll
  for (int o = 0; o < 32; ++o) acc[o] = 0.f;

  const float4* mb4 = (const float4*)mem + (size_t)b * 16384;
  for (int c0 = 0; c0 < 256; c0 += 32) {
#pragma unroll
    for (int i = 0; i < 8; ++i)
      ((float4*)lm)[i * 256 + t] = mb4[c0 * 64 + i * 256 + t];
    __syncthreads();
    for (int cl = 0; cl < 32; ++cl) {
      float m[9];
#pragma unroll
      for (int i = 0; i < 9; ++i) m[i] = msk[i] * lm[cl * 256 + nid[i]];
      const float* w = k1 + (size_t)(c0 + cl) * 32;   // + tap*8192 + o
#pragma unroll
      for (int tap = 0; tap < 9; ++tap) {
        const float* wt = w + tap * 8192;             // uniform -> s_load
        float mt = m[tap];
#pragma unroll
        for (int o = 0; o < 32; ++o) acc[o] += mt * wt[o];
      }
    }
    __syncthreads();
  }
  float* hb = h1 + (size_t)b * 8192;
#pragma unroll
  for (int o = 0; o < 32; ++o) hb[o * 256 + t] = acc[o];
}

// -------- conv2 (VALID, 32->64, 14x14) + 2x2 s1 avgpool -> flat (B,10816) --
__global__ __launch_bounds__(256) void conv2_pool_kernel(
    const float* __restrict__ h1, const float* __restrict__ k2,
    float* __restrict__ flat) {
  const int b = blockIdx.x;
  const int t = threadIdx.x;
  __shared__ float lh1[32 * 256];
  __shared__ float lh2[32 * 196];
  const float4* hb4 = (const float4*)(h1 + (size_t)b * 8192);
#pragma unroll
  for (int i = 0; i < 8; ++i) ((float4*)lh1)[i * 256 + t] = hb4[i * 256 + t];
  __syncthreads();
  const int yy = t / 14, xx = t - yy * 14;  // valid when t<196
  for (int oh = 0; oh < 2; ++oh) {
    if (t < 196) {
      float acc[32];
#pragma unroll
      for (int o = 0; o < 32; ++o) acc[o] = 0.f;
      for (int c = 0; c < 32; ++c) {
        float m[9];
#pragma unroll
        for (int dy = 0; dy < 3; ++dy)
#pragma unroll
          for (int dx = 0; dx < 3; ++dx)
            m[dy * 3 + dx] = lh1[c * 256 + (yy + dy) * 16 + (xx + dx)];
        const float* w = k2 + (size_t)c * 64 + oh * 32;  // + tap*2048 + o
#pragma unroll
        for (int tap = 0; tap < 9; ++tap) {
          const float* wt = w + tap * 2048;              // uniform -> s_load
          float mt = m[tap];
#pragma unroll
          for (int o = 0; o < 32; ++o) acc[o] += mt * wt[o];
        }
      }
#pragma unroll
      for (int o = 0; o < 32; ++o) lh2[o * 196 + t] = acc[o];
    }
    __syncthreads();
    for (int e = t; e < 32 * 169; e += 256) {
      int o = e / 169, pe = e - o * 169;
      int py = pe / 13, px = pe - py * 13;
      int base = o * 196 + py * 14 + px;
      float v = 0.25f * (lh2[base] + lh2[base + 1] + lh2[base + 14] + lh2[base + 15]);
      flat[(size_t)b * FLATD + (size_t)(oh * 32 + o) * 169 + pe] = v;
    }
    __syncthreads();
  }
}

// ---------------- dense1: flat(1024,10816) @ W1(10816,128), K-split -------
__global__ __launch_bounds__(256) void dense1_kernel(
    const float* __restrict__ flat, const float* __restrict__ W1,
    float* __restrict__ T1p) {
  const int bt = blockIdx.x, ks = blockIdx.y;
  const int t = threadIdx.x;
  __shared__ float lA[64 * 64];
  __shared__ float lB[64 * 128];
  const int m0 = (t >> 5) * 8, n0 = (t & 31) * 4;
  const int b0 = bt * 64, kbase = ks * KCH;
  float4 acc[8];
#pragma unroll
  for (int i = 0; i < 8; ++i) acc[i] = make_float4(0.f, 0.f, 0.f, 0.f);
  for (int s = 0; s < 6; ++s) {
    const int k0 = s * 64;
#pragma unroll
    for (int i = 0; i < 16; ++i) {
      int e = i * 256 + t, r = e >> 6, c = e & 63;
      lA[e] = (k0 + c < KCH) ? flat[(size_t)(b0 + r) * FLATD + kbase + k0 + c] : 0.f;
    }
#pragma unroll
    for (int i = 0; i < 32; ++i) {
      int e = i * 256 + t, r = e >> 7, c = e & 127;
      lB[e] = (k0 + r < KCH) ? W1[(size_t)(kbase + k0 + r) * 128 + c] : 0.f;
    }
    __syncthreads();
    for (int kk = 0; kk < 64; ++kk) {
      float a[8];
#pragma unroll
      for (int i = 0; i < 8; ++i) a[i] = lA[(m0 + i) * 64 + kk];
      float4 bv = *(const float4*)&lB[kk * 128 + n0];
#pragma unroll
      for (int i = 0; i < 8; ++i) {
        acc[i].x += a[i] * bv.x; acc[i].y += a[i] * bv.y;
        acc[i].z += a[i] * bv.z; acc[i].w += a[i] * bv.w;
      }
    }
    __syncthreads();
  }
#pragma unroll
  for (int i = 0; i < 8; ++i)
    *(float4*)&T1p[((size_t)ks * 1024 + b0 + m0 + i) * 128 + n0] = acc[i];
}

// -------- reduce partials, dense2 -> r_t, then q_t = [ctx|r_t]@CK ---------
__global__ __launch_bounds__(256) void dense2_qt_kernel(
    const float* __restrict__ T1p, const float* __restrict__ W2,
    const float* __restrict__ ctx, const float* __restrict__ CK,
    float* __restrict__ rt, float* __restrict__ qt) {
  const int bt = blockIdx.x;  // 16 batches per block
  const int t = threadIdx.x;
  const int b0 = bt * 16;
  __shared__ float lT[16 * 128];
  __shared__ float lc[16 * 256];
  __shared__ float lr[16 * 256];
  __shared__ float lw[32 * 256];
#pragma unroll
  for (int i = 0; i < 8; ++i) {
    int e = i * 256 + t, r = e >> 7, c = e & 127;
    float s = 0.f;
    for (int ks = 0; ks < KS; ++ks)
      s += T1p[((size_t)ks * 1024 + b0 + r) * 128 + c];
    lT[e] = s;
  }
#pragma unroll
  for (int i = 0; i < 16; ++i) {
    int e = i * 256 + t, r = e >> 8, c = e & 255;
    lc[e] = ctx[(size_t)(b0 + r) * 256 + c];
  }
  __syncthreads();
  const int m = t >> 4;
  const int n0 = (t & 15) * 4;  // cols n0 + j*64
  float4 acc[4];
#pragma unroll
  for (int j = 0; j < 4; ++j) acc[j] = make_float4(0.f, 0.f, 0.f, 0.f);
  for (int k0 = 0; k0 < 128; k0 += 32) {
#pragma unroll
    for (int i = 0; i < 32; ++i) {
      int e = i * 256 + t, r = e >> 8, c = e & 255;
      lw[e] = W2[(size_t)(k0 + r) * 256 + c];
    }
    __syncthreads();
    for (int kk = 0; kk < 32; ++kk) {
      float a = lT[m * 128 + k0 + kk];
#pragma unroll
      for (int j = 0; j < 4; ++j) {
        float4 w = *(const float4*)&lw[kk * 256 + n0 + j * 64];
        acc[j].x += a * w.x; acc[j].y += a * w.y;
        acc[j].z += a * w.z; acc[j].w += a * w.w;
      }
    }
    __syncthreads();
  }
#pragma unroll
  for (int j = 0; j < 4; ++j) {
    *(float4*)&lr[m * 256 + n0 + j * 64] = acc[j];
    *(float4*)&rt[(size_t)(b0 + m) * 256 + n0 + j * 64] = acc[j];
  }
  __syncthreads();
  float4 qa[4];
#pragma unroll
  for (int j = 0; j < 4; ++j) qa[j] = make_float4(0.f, 0.f, 0.f, 0.f);
  for (int k0 = 0; k0 < 512; k0 += 32) {
#pragma unroll
    for (int i = 0; i < 32; ++i) {
      int e = i * 256 + t, r = e >> 8, c = e & 255;
      lw[e] = CK[(size_t)(k0 + r) * 256 + c];
    }
    __syncthreads();
    const float* abase = (k0 < 256) ? &lc[m * 256 + k0] : &lr[m * 256 + k0 - 256];
    for (int kk = 0; kk < 32; ++kk) {
      float a = abase[kk];
#pragma unroll
      for (int j = 0; j < 4; ++j) {
        float4 w = *(const float4*)&lw[kk * 256 + n0 + j * 64];
        qa[j].x += a * w.x; qa[j].y += a * w.y;
        qa[j].z += a * w.z; qa[j].w += a * w.w;
      }
    }
    __syncthreads();
  }
#pragma unroll
  for (int j = 0; j < 4; ++j)
    *(float4*)&qt[(size_t)(b0 + m) * 256 + n0 + j * 64] = qa[j];
}

// ---------------- attention: at=q.mem, normalize, c_t=at.mem --------------
__global__ __launch_bounds__(256) void attn_kernel(
    const float* __restrict__ qt, const float* __restrict__ mem,
    float* __restrict__ ct) {
  const int b = blockIdx.x;
  const int t = threadIdx.x;
  const float* mb = mem + (size_t)b * 65536;
  const float* qb = qt + (size_t)b * 256;   // uniform -> s_load
  __shared__ float latn[256];
  __shared__ float lp[4];
  float acc = 0.f;
#pragma unroll 8
  for (int c = 0; c < 256; ++c) acc += qb[c] * mb[(size_t)c * 256 + t];
  float v = acc;
#pragma unroll
  for (int off = 32; off; off >>= 1) v += __shfl_xor(v, off, 64);
  if ((t & 63) == 0) lp[t >> 6] = v;
  __syncthreads();
  float den = lp[0] + lp[1] + lp[2] + lp[3];
  latn[t] = acc / den;
  __syncthreads();
  const int wid = t >> 6, lane = t & 63;
  float a0 = latn[lane], a1 = latn[64 + lane], a2 = latn[128 + lane], a3 = latn[192 + lane];
  for (int i = 0; i < 64; ++i) {
    int ch = wid * 64 + i;
    const float* r = mb + (size_t)ch * 256;
    float v2 = a0 * r[lane] + a1 * r[64 + lane] + a2 * r[128 + lane] + a3 * r[192 + lane];
#pragma unroll
    for (int off = 32; off; off >>= 1) v2 += __shfl_xor(v2, off, 64);
    if (lane == 0) ct[(size_t)b * 256 + ch] = v2;
  }
}

// ------- final: s_t, imps, write update, copy memory with one-pixel set ---
__global__ __launch_bounds__(256) void final_kernel(
    const float* __restrict__ mem, const float* __restrict__ ctx,
    const float* __restrict__ RK, const int* __restrict__ pos,
    const float* __restrict__ ct, const float* __restrict__ rt,
    float* __restrict__ nm) {
  const int b = blockIdx.x;
  const int t = threadIdx.x;
  __shared__ float ls[256], ld[256], ln[256];
  __shared__ float lp1[4], lp2[4];
  const float* cb = ctx + (size_t)b * 256;  // uniform -> s_load
  float sacc = 0.f;
#pragma unroll 8
  for (int k = 0; k < 256; ++k) sacc += cb[k] * RK[(size_t)k * 256 + t];
  ls[t] = sacc;
  const int px = pos[2 * b], py = pos[2 * b + 1];
  const int pstar = py * 16 + px;
  float mt = mem[(size_t)b * 65536 + (size_t)t * 256 + pstar];
  float rv = rt[(size_t)b * 256 + t];
  float cv = ct[(size_t)b * 256 + t];
  float v1 = sacc * rv;   // -> global_imp
  float v2 = sacc * cv;   // -> local_imp
#pragma unroll
  for (int off = 32; off; off >>= 1) {
    v1 += __shfl_xor(v1, off, 64);
    v2 += __shfl_xor(v2, off, 64);
  }
  if ((t & 63) == 0) { lp1[t >> 6] = v1; lp2[t >> 6] = v2; }
  ld[t] = mt - sacc;
  __syncthreads();
  float gsum = lp1[0] + lp1[1] + lp1[2] + lp1[3];
  float lsum = lp2[0] + lp2[1] + lp2[2] + lp2[3];
  float uacc = 0.f;
  const float* RK2 = RK + 65536;  // write_update rows
#pragma unroll 8
  for (int k = 0; k < 256; ++k) uacc += ld[k] * RK2[(size_t)k * 256 + t];
  float f = lsum / (lsum + gsum);
  ln[t] = mt + f * uacc;
  __syncthreads();
  const float4* src = (const float4*)(mem + (size_t)b * 65536);
  float4* dst = (float4*)(nm + (size_t)b * 65536);
  const int q = pstar >> 2, rsub = pstar & 3;
#pragma unroll
  for (int i = 0; i < 64; ++i) {
    int fi = i * 256 + t;
    float4 v = src[fi];
    if ((fi & 63) == q) ((float*)&v)[rsub] = ln[fi >> 6];
    dst[fi] = v;
  }
}

extern "C" void kernel_launch(void* const* d_in, const int* in_sizes, int n_in,
                              void* d_out, int out_size, void* d_ws, size_t ws_size,
                              hipStream_t stream) {
  const float* ctx = (const float*)d_in[0];
  const float* mem = (const float*)d_in[1];
  const int*   pos = (const int*)d_in[2];
  const float* k1  = (const float*)d_in[3];
  const float* k2  = (const float*)d_in[4];
  const float* W1  = (const float*)d_in[5];
  const float* W2  = (const float*)d_in[6];
  const float* CK  = (const float*)d_in[7];
  const float* RK  = (const float*)d_in[8];
  float* out = (float*)d_out;
  float* ct = out;
  float* rt = out + 262144;
  float* nm = out + 524288;          // B*256*256 floats; also scratch until final
  float* h1   = nm;                  // 8,388,608 floats
  float* flat = nm + 8388608;        // 11,075,584 floats
  float* T1p  = nm + 19464192;       // 4,194,304 floats
  float* qt   = nm + 23658496;       // 262,144 floats

  conv1_kernel<<<1024, 256, 0, stream>>>(mem, k1, h1);
  conv2_pool_kernel<<<1024, 256, 0, stream>>>(h1, k2, flat);
  dense1_kernel<<<dim3(16, KS), 256, 0, stream>>>(flat, W1, T1p);
  dense2_qt_kernel<<<64, 256, 0, stream>>>(T1p, W2, ctx, CK, rt, qt);
  attn_kernel<<<1024, 256, 0, stream>>>(qt, mem, ct);
  final_kernel<<<1024, 256, 0, stream>>>(mem, ctx, RK, pos, ct, rt, nm);
}

// Round 2
// 919.051 us; speedup vs baseline: 1.3709x; 1.3709x over previous
//
#include <hip/hip_runtime.h>

#define FLATD 10816
#define KS 32
#define KCH 338   // 10816 / 32

// ---------------- conv1: memory (B,256,16,16) -> h1 (B,32,16,16), SAME ----
// 512 threads: t<256 -> out ch 0..15 of pixel t; t>=256 -> out ch 16..31.
// Halo-padded LDS tile (18x18, zeroed border) removes mask multiplies.
__global__ __launch_bounds__(512, 8) void conv1_kernel(
    const float* __restrict__ mem, const float* __restrict__ k1,
    float* __restrict__ h1) {
  const int b = blockIdx.x;
  const int t = threadIdx.x;              // 0..511
  const int p = t & 255;
  const int y = p >> 4, x = p & 15;
  const int o0 = __builtin_amdgcn_readfirstlane((t >> 8) * 16);  // 0 or 16
  __shared__ float lm[16 * 324];          // 16 ch x (18x18) padded

  for (int e = t; e < 16 * 324; e += 512) lm[e] = 0.f;  // halo stays zero

  float acc[16];
#pragma unroll
  for (int o = 0; o < 16; ++o) acc[o] = 0.f;
  __syncthreads();

  const float4* mb4 = (const float4*)(mem + (size_t)b * 65536);
  for (int c0 = 0; c0 < 256; c0 += 16) {
    // stage 16 channels: 1024 float4 loads, interior of padded tile
#pragma unroll
    for (int i = 0; i < 2; ++i) {
      int e = i * 512 + t;                // 0..1023
      int ch = e >> 6;                    // 0..15
      int q4 = e & 63;                    // float4 index within channel
      float4 v = mb4[(size_t)(c0 + ch) * 64 + q4];
      int p4 = q4 << 2;
      int dst = ch * 324 + (p4 >> 4) * 18 + (p4 & 15) + 19;
      lm[dst] = v.x; lm[dst + 1] = v.y; lm[dst + 2] = v.z; lm[dst + 3] = v.w;
    }
    __syncthreads();
    for (int cl = 0; cl < 16; ++cl) {
      const float* base = &lm[cl * 324 + y * 18 + x];
      float m[9];
      m[0] = base[0];  m[1] = base[1];  m[2] = base[2];
      m[3] = base[18]; m[4] = base[19]; m[5] = base[20];
      m[6] = base[36]; m[7] = base[37]; m[8] = base[38];
      const float* w = k1 + (size_t)(c0 + cl) * 32 + o0;
#pragma unroll
      for (int tap = 0; tap < 9; ++tap) {
        const float* wt = w + (size_t)tap * 8192;   // wave-uniform -> s_load
        float mt = m[tap];
#pragma unroll
        for (int o = 0; o < 16; ++o) acc[o] += mt * wt[o];
      }
    }
    __syncthreads();
  }
  float* hb = h1 + (size_t)b * 8192 + (size_t)o0 * 256;
#pragma unroll
  for (int o = 0; o < 16; ++o) hb[o * 256 + p] = acc[o];
}

// -------- conv2 (VALID, 32->64, 14x14) + 2x2 s1 avgpool -> flat (B,10816) --
// grid 2048: block = (batch, oh half). 32 outputs/thread, chunked LDS.
__global__ __launch_bounds__(256) void conv2_pool_kernel(
    const float* __restrict__ h1, const float* __restrict__ k2,
    float* __restrict__ flat) {
  const int bid = blockIdx.x;
  const int b = bid >> 1, oh = bid & 1;
  const int t = threadIdx.x;
  __shared__ float lh1[16 * 256];
  __shared__ float lh2[8 * 196];
  const int yy = t / 14, xx = t - yy * 14;   // valid when t<196
  float acc[32];
#pragma unroll
  for (int o = 0; o < 32; ++o) acc[o] = 0.f;

  const float4* hb4 = (const float4*)(h1 + (size_t)b * 8192);
  for (int c0 = 0; c0 < 32; c0 += 16) {
#pragma unroll
    for (int i = 0; i < 4; ++i)
      ((float4*)lh1)[i * 256 + t] = hb4[(size_t)c0 * 64 + i * 256 + t];
    __syncthreads();
    if (t < 196) {
      for (int cl = 0; cl < 16; ++cl) {
        const float* base = &lh1[cl * 256 + yy * 16 + xx];
        float m[9];
        m[0] = base[0];  m[1] = base[1];  m[2] = base[2];
        m[3] = base[16]; m[4] = base[17]; m[5] = base[18];
        m[6] = base[32]; m[7] = base[33]; m[8] = base[34];
        const float* w = k2 + (size_t)(c0 + cl) * 64 + oh * 32;
#pragma unroll
        for (int tap = 0; tap < 9; ++tap) {
          const float* wt = w + (size_t)tap * 2048;  // uniform -> s_load
          float mt = m[tap];
#pragma unroll
          for (int o = 0; o < 32; ++o) acc[o] += mt * wt[o];
        }
      }
    }
    __syncthreads();
  }
  // pool 2x2 stride-1 in 4 chunks of 8 channels
  for (int ck = 0; ck < 4; ++ck) {
    if (t < 196)
#pragma unroll
      for (int o = 0; o < 8; ++o) lh2[o * 196 + t] = acc[ck * 8 + o];
    __syncthreads();
    for (int e = t; e < 8 * 169; e += 256) {
      int o = e / 169, pe = e - o * 169;
      int py = pe / 13, px = pe - py * 13;
      int base = o * 196 + py * 14 + px;
      float v = 0.25f * (lh2[base] + lh2[base + 1] + lh2[base + 14] + lh2[base + 15]);
      flat[(size_t)b * FLATD + (size_t)(oh * 32 + ck * 8 + o) * 169 + pe] = v;
    }
    __syncthreads();
  }
}

// ---------------- dense1: flat(1024,10816) @ W1(10816,128), K-split -------
__global__ __launch_bounds__(256) void dense1_kernel(
    const float* __restrict__ flat, const float* __restrict__ W1,
    float* __restrict__ T1p) {
  const int bt = blockIdx.x, ks = blockIdx.y;
  const int t = threadIdx.x;
  __shared__ float lA[64 * 64];
  __shared__ float lB[64 * 128];
  const int m0 = (t >> 5) * 8, n0 = (t & 31) * 4;
  const int b0 = bt * 64, kbase = ks * KCH;
  float4 acc[8];
#pragma unroll
  for (int i = 0; i < 8; ++i) acc[i] = make_float4(0.f, 0.f, 0.f, 0.f);
  for (int s = 0; s < 6; ++s) {
    const int k0 = s * 64;
#pragma unroll
    for (int i = 0; i < 16; ++i) {
      int e = i * 256 + t, r = e >> 6, c = e & 63;
      lA[e] = (k0 + c < KCH) ? flat[(size_t)(b0 + r) * FLATD + kbase + k0 + c] : 0.f;
    }
#pragma unroll
    for (int i = 0; i < 32; ++i) {
      int e = i * 256 + t, r = e >> 7, c = e & 127;
      lB[e] = (k0 + r < KCH) ? W1[(size_t)(kbase + k0 + r) * 128 + c] : 0.f;
    }
    __syncthreads();
    for (int kk = 0; kk < 64; ++kk) {
      float a[8];
#pragma unroll
      for (int i = 0; i < 8; ++i) a[i] = lA[(m0 + i) * 64 + kk];
      float4 bv = *(const float4*)&lB[kk * 128 + n0];
#pragma unroll
      for (int i = 0; i < 8; ++i) {
        acc[i].x += a[i] * bv.x; acc[i].y += a[i] * bv.y;
        acc[i].z += a[i] * bv.z; acc[i].w += a[i] * bv.w;
      }
    }
    __syncthreads();
  }
#pragma unroll
  for (int i = 0; i < 8; ++i)
    *(float4*)&T1p[((size_t)ks * 1024 + b0 + m0 + i) * 128 + n0] = acc[i];
}

// -------- reduce partials, dense2 -> r_t, then q_t = [ctx|r_t]@CK ---------
__global__ __launch_bounds__(256) void dense2_qt_kernel(
    const float* __restrict__ T1p, const float* __restrict__ W2,
    const float* __restrict__ ctx, const float* __restrict__ CK,
    float* __restrict__ rt, float* __restrict__ qt) {
  const int bt = blockIdx.x;  // 16 batches per block
  const int t = threadIdx.x;
  const int b0 = bt * 16;
  __shared__ float lT[16 * 128];
  __shared__ float lc[16 * 256];
  __shared__ float lr[16 * 256];
  __shared__ float lw[32 * 256];
#pragma unroll
  for (int i = 0; i < 8; ++i) {
    int e = i * 256 + t, r = e >> 7, c = e & 127;
    float s = 0.f;
    for (int ks = 0; ks < KS; ++ks)
      s += T1p[((size_t)ks * 1024 + b0 + r) * 128 + c];
    lT[e] = s;
  }
#pragma unroll
  for (int i = 0; i < 16; ++i) {
    int e = i * 256 + t, r = e >> 8, c = e & 255;
    lc[e] = ctx[(size_t)(b0 + r) * 256 + c];
  }
  __syncthreads();
  const int m = t >> 4;
  const int n0 = (t & 15) * 4;  // cols n0 + j*64
  float4 acc[4];
#pragma unroll
  for (int j = 0; j < 4; ++j) acc[j] = make_float4(0.f, 0.f, 0.f, 0.f);
  for (int k0 = 0; k0 < 128; k0 += 32) {
#pragma unroll
    for (int i = 0; i < 32; ++i) {
      int e = i * 256 + t, r = e >> 8, c = e & 255;
      lw[e] = W2[(size_t)(k0 + r) * 256 + c];
    }
    __syncthreads();
    for (int kk = 0; kk < 32; ++kk) {
      float a = lT[m * 128 + k0 + kk];
#pragma unroll
      for (int j = 0; j < 4; ++j) {
        float4 w = *(const float4*)&lw[kk * 256 + n0 + j * 64];
        acc[j].x += a * w.x; acc[j].y += a * w.y;
        acc[j].z += a * w.z; acc[j].w += a * w.w;
      }
    }
    __syncthreads();
  }
#pragma unroll
  for (int j = 0; j < 4; ++j) {
    *(float4*)&lr[m * 256 + n0 + j * 64] = acc[j];
    *(float4*)&rt[(size_t)(b0 + m) * 256 + n0 + j * 64] = acc[j];
  }
  __syncthreads();
  float4 qa[4];
#pragma unroll
  for (int j = 0; j < 4; ++j) qa[j] = make_float4(0.f, 0.f, 0.f, 0.f);
  for (int k0 = 0; k0 < 512; k0 += 32) {
#pragma unroll
    for (int i = 0; i < 32; ++i) {
      int e = i * 256 + t, r = e >> 8, c = e & 255;
      lw[e] = CK[(size_t)(k0 + r) * 256 + c];
    }
    __syncthreads();
    const float* abase = (k0 < 256) ? &lc[m * 256 + k0] : &lr[m * 256 + k0 - 256];
    for (int kk = 0; kk < 32; ++kk) {
      float a = abase[kk];
#pragma unroll
      for (int j = 0; j < 4; ++j) {
        float4 w = *(const float4*)&lw[kk * 256 + n0 + j * 64];
        qa[j].x += a * w.x; qa[j].y += a * w.y;
        qa[j].z += a * w.z; qa[j].w += a * w.w;
      }
    }
    __syncthreads();
  }
#pragma unroll
  for (int j = 0; j < 4; ++j)
    *(float4*)&qt[(size_t)(b0 + m) * 256 + n0 + j * 64] = qa[j];
}

// ------ fused attention + final: at, c_t, s_t, imps, memory write-back ----
__global__ __launch_bounds__(256) void attn_final_kernel(
    const float* __restrict__ qt, const float* __restrict__ mem,
    const float* __restrict__ ctx, const float* __restrict__ RK,
    const int* __restrict__ pos, const float* __restrict__ rt,
    float* __restrict__ ct, float* __restrict__ nm) {
  const int b = blockIdx.x;
  const int t = threadIdx.x;
  const float* mb = mem + (size_t)b * 65536;
  const float* qb = qt + (size_t)b * 256;   // uniform -> s_load
  __shared__ float latn[256], lct[256], ld[256], ln[256];
  __shared__ float lp[4], lp1[4], lp2[4];
  // ---- at = q . mem (per pixel t), den = sum
  float acc = 0.f;
#pragma unroll 8
  for (int c = 0; c < 256; ++c) acc += qb[c] * mb[(size_t)c * 256 + t];
  float v = acc;
#pragma unroll
  for (int off = 32; off; off >>= 1) v += __shfl_xor(v, off, 64);
  if ((t & 63) == 0) lp[t >> 6] = v;
  __syncthreads();
  float den = lp[0] + lp[1] + lp[2] + lp[3];
  latn[t] = acc / den;
  __syncthreads();
  // ---- c_t = sum_p at[p] * mem[c][p]
  const int wid = t >> 6, lane = t & 63;
  float a0 = latn[lane], a1 = latn[64 + lane], a2 = latn[128 + lane], a3 = latn[192 + lane];
  for (int i = 0; i < 64; ++i) {
    int ch = wid * 64 + i;
    const float* r = mb + (size_t)ch * 256;
    float v2 = a0 * r[lane] + a1 * r[64 + lane] + a2 * r[128 + lane] + a3 * r[192 + lane];
#pragma unroll
    for (int off = 32; off; off >>= 1) v2 += __shfl_xor(v2, off, 64);
    if (lane == 0) { ct[(size_t)b * 256 + ch] = v2; lct[ch] = v2; }
  }
  // ---- s_t = ctx @ write_kernel   (column t)
  const float* cb = ctx + (size_t)b * 256;  // uniform -> s_load
  float sacc = 0.f;
#pragma unroll 8
  for (int k = 0; k < 256; ++k) sacc += cb[k] * RK[(size_t)k * 256 + t];
  const int px = pos[2 * b], py = pos[2 * b + 1];
  const int pstar = py * 16 + px;
  float mt = mb[(size_t)t * 256 + pstar];
  float rv = rt[(size_t)b * 256 + t];
  __syncthreads();              // lct visible
  float cv = lct[t];
  float v1 = sacc * rv;   // -> global_imp
  float v2 = sacc * cv;   // -> local_imp
#pragma unroll
  for (int off = 32; off; off >>= 1) {
    v1 += __shfl_xor(v1, off, 64);
    v2 += __shfl_xor(v2, off, 64);
  }
  if ((t & 63) == 0) { lp1[t >> 6] = v1; lp2[t >> 6] = v2; }
  ld[t] = mt - sacc;
  __syncthreads();
  float gsum = lp1[0] + lp1[1] + lp1[2] + lp1[3];
  float lsum = lp2[0] + lp2[1] + lp2[2] + lp2[3];
  float uacc = 0.f;
  const float* RK2 = RK + 65536;  // write_update rows
#pragma unroll 8
  for (int k = 0; k < 256; ++k) uacc += ld[k] * RK2[(size_t)k * 256 + t];
  float f = lsum / (lsum + gsum);
  ln[t] = mt + f * uacc;
  __syncthreads();
  // ---- copy memory -> new_memory with single-pixel substitution
  const float4* src = (const float4*)mb;
  float4* dst = (float4*)(nm + (size_t)b * 65536);
  const int q = pstar >> 2, rsub = pstar & 3;
#pragma unroll
  for (int i = 0; i < 64; ++i) {
    int fi = i * 256 + t;
    float4 vv = src[fi];
    if ((fi & 63) == q) ((float*)&vv)[rsub] = ln[fi >> 6];
    dst[fi] = vv;
  }
}

extern "C" void kernel_launch(void* const* d_in, const int* in_sizes, int n_in,
                              void* d_out, int out_size, void* d_ws, size_t ws_size,
                              hipStream_t stream) {
  const float* ctx = (const float*)d_in[0];
  const float* mem = (const float*)d_in[1];
  const int*   pos = (const int*)d_in[2];
  const float* k1  = (const float*)d_in[3];
  const float* k2  = (const float*)d_in[4];
  const float* W1  = (const float*)d_in[5];
  const float* W2  = (const float*)d_in[6];
  const float* CK  = (const float*)d_in[7];
  const float* RK  = (const float*)d_in[8];
  float* out = (float*)d_out;
  float* ct = out;
  float* rt = out + 262144;
  float* nm = out + 524288;          // B*256*256 floats; also scratch until final
  float* h1   = nm;                  // 8,388,608 floats
  float* flat = nm + 8388608;        // 11,075,584 floats
  float* T1p  = nm + 19464192;       // 4,194,304 floats
  float* qt   = nm + 23658496;       // 262,144 floats

  conv1_kernel<<<1024, 512, 0, stream>>>(mem, k1, h1);
  conv2_pool_kernel<<<2048, 256, 0, stream>>>(h1, k2, flat);
  dense1_kernel<<<dim3(16, KS), 256, 0, stream>>>(flat, W1, T1p);
  dense2_qt_kernel<<<64, 256, 0, stream>>>(T1p, W2, ctx, CK, rt, qt);
  attn_final_kernel<<<1024, 256, 0, stream>>>(qt, mem, ctx, RK, pos, rt, ct, nm);
}